// Round 2
// baseline (16229.047 us; speedup 1.0000x reference)
//
#include <hip/hip_runtime.h>
#include <math.h>

constexpr int cH  = 256;
constexpr int cS  = 64;
constexpr int cAN = 16;
constexpr int cD  = 8;
constexpr int cT  = 32;
constexpr int cN  = 64;
constexpr int cHG = 770;
constexpr int cG3 = 2310;
constexpr int cOW = 338;
constexpr int GRID = 256;
constexpr int KP   = 784;   // padded HG (7*112)
constexpr int CK   = 112;   // GRU k-chunk
constexpr int NCH  = 7;     // KP/CK

union Sh {
  struct { float w[12][788]; float hs[64][116]; } gru;           // 67.5 KB
  struct { float As[16][68]; float Bs[16][68]; } ge;
  struct { float rs[256]; float bs[512]; float wt[32][260]; float w0s[32][12]; } c0;
  struct { float ss[256]; float es[256]; float red[256];
           float lg[16]; float dpv[16]; float nz[16]; float pr[16];
           float pss[64]; float red64[64]; float mxs[2]; int anynz; } tl;
};

__device__ __forceinline__ void gbar(int* cnt, int* gen) {
  __syncthreads();
  if (threadIdx.x == 0) {
    int g = __hip_atomic_load(gen, __ATOMIC_RELAXED, __HIP_MEMORY_SCOPE_AGENT);
    int a = __hip_atomic_fetch_add(cnt, 1, __ATOMIC_ACQ_REL, __HIP_MEMORY_SCOPE_AGENT);
    if (a == GRID - 1) {
      __hip_atomic_store(cnt, 0, __ATOMIC_RELAXED, __HIP_MEMORY_SCOPE_AGENT);
      __hip_atomic_fetch_add(gen, 1, __ATOMIC_ACQ_REL, __HIP_MEMORY_SCOPE_AGENT);
    } else {
      while (__hip_atomic_load(gen, __ATOMIC_ACQUIRE, __HIP_MEMORY_SCOPE_AGENT) == g) {
        __builtin_amdgcn_s_sleep(1);
      }
    }
  }
  __syncthreads();
}

// softmax(p[n]) -> psb, r[n] = ps @ M[n]   (one block, 256 threads)
__device__ __forceinline__ void ps_r_compute(int n, const float* p, const float* X,
                                             float* psb, float* r,
                                             float* pss, float* red, float* mxs) {
  int tid = threadIdx.x;
  if (tid < cS) red[tid] = p[n * cS + tid];
  __syncthreads();
  if (tid == 0) { float m = red[0]; for (int i = 1; i < cS; ++i) m = fmaxf(m, red[i]); mxs[0] = m; }
  __syncthreads();
  if (tid < cS) red[tid] = expf(red[tid] - mxs[0]);
  __syncthreads();
  if (tid == 0) { float s = 0.f; for (int i = 0; i < cS; ++i) s += red[i]; mxs[1] = s; }
  __syncthreads();
  if (tid < cS) { pss[tid] = red[tid] / mxs[1]; psb[n * cS + tid] = pss[tid]; }
  __syncthreads();
  float acc = 0.f;
  for (int s2 = 0; s2 < cS; ++s2)
    acc += pss[s2] * X[((size_t)(n * cS + s2)) * cHG + 2 + tid];
  r[n * cH + tid] = acc;
}

__global__ __launch_bounds__(256, 2) void k_fused(
    const float* __restrict__ base, const float* __restrict__ inter,
    const float* __restrict__ hxs, const float* __restrict__ emb,
    const float* __restrict__ w_ih, const float* __restrict__ w_hh,
    const float* __restrict__ b_ih, const float* __restrict__ b_hh,
    const float* __restrict__ conv0_w, const float* __restrict__ conv0_b,
    const float* __restrict__ convs_w, const float* __restrict__ convs_b,
    const float* __restrict__ lin_w, const float* __restrict__ lin_b,
    const float* __restrict__ psi_w, const float* __restrict__ psi_b,
    const float* __restrict__ actor_w, const float* __restrict__ actor_b,
    const float* __restrict__ critic_w, const float* __restrict__ critic_b,
    const int* __restrict__ subtasks, const int* __restrict__ actions,
    float* __restrict__ out,
    int* cnt, int* gen,
    float* __restrict__ gitab, float* __restrict__ X, float* __restrict__ psip,
    float* __restrict__ p, float* __restrict__ psb, float* __restrict__ r,
    float* __restrict__ nMp, float* __restrict__ nMm,
    float* __restrict__ x1, float* __restrict__ x2, float* __restrict__ x3t) {
  __shared__ Sh sh;
  const int bid = blockIdx.x, tid = threadIdx.x;
  float* part = x1;  // lin partials alias x1 (x1 dead after x2-GEMM; barrier-separated)

  // ---------------- phase 0: gitab, psip perm, whh -> LDS ----------------
  for (int work = bid; work < 320; work += GRID) {   // 32 v * 10 j-blocks
    int v = work / 10, jb = work % 10;
    int j = jb * 256 + tid;
    if (j < cG3) {
      float acc = b_ih[j];
      const float* wr = w_ih + (size_t)j * cH;
      const float* er = emb + (size_t)v * cH;
      #pragma unroll 8
      for (int h = 0; h < cH; ++h) acc += wr[h] * er[h];
      gitab[(size_t)v * cG3 + j] = acc;
    }
  }
  #pragma unroll
  for (int q = 0; q < 16; ++q) {
    int idx = bid * 4096 + q * 256 + tid;            // 256*4096 = 1048576
    int a = idx >> 16, h = (idx >> 8) & 255, o = idx & 255;
    psip[idx] = psi_w[((size_t)o * cH + h) * cAN + a];
  }
  if (bid < 193) {
    for (int idx = tid; idx < 12 * KP; idx += 256) {
      int row = idx / KP, kp = idx % KP;
      int g = row >> 2, kl = row & 3;
      int kg = bid * 4 + kl;
      float v = 0.f;
      if (kg < cHG && kp < cHG) v = w_hh[((size_t)(g * cHG + kg)) * cHG + kp];
      sh.gru.w[row][kp] = v;
    }
  }
  gbar(cnt, gen);

  // ---------------- phase 1: GRU, 64 steps, weight-stationary ----------------
  for (int s = 0; s < cS; ++s) {
    if (bid < 193) {
      int m = tid & 63, kl = tid >> 6;
      float accr = 0.f, accz = 0.f, accn = 0.f;
      if (s > 0) {
        for (int c = 0; c < NCH; ++c) {
          int kc = c * CK;
          #pragma unroll
          for (int q = 0; q < 7; ++q) {
            int idx = q * 256 + tid;                 // 0..1791 = 64 m * 28 f4
            int mm = idx / 28, c4 = (idx % 28) * 4;
            // may read up to 14 floats past a 770-row: multiplied by zero weights
            float4 v = *(const float4*)(X + ((size_t)(mm * cS + (s - 1))) * cHG + kc + c4);
            *(float4*)&sh.gru.hs[mm][c4] = v;
          }
          __syncthreads();
          #pragma unroll 4
          for (int j = 0; j < 28; ++j) {
            float4 h4 = *(const float4*)&sh.gru.hs[m][4 * j];
            float4 w0 = *(const float4*)&sh.gru.w[kl][kc + 4 * j];
            float4 w1 = *(const float4*)&sh.gru.w[4 + kl][kc + 4 * j];
            float4 w2 = *(const float4*)&sh.gru.w[8 + kl][kc + 4 * j];
            accr += h4.x * w0.x + h4.y * w0.y + h4.z * w0.z + h4.w * w0.w;
            accz += h4.x * w1.x + h4.y * w1.y + h4.z * w1.z + h4.w * w1.w;
            accn += h4.x * w2.x + h4.y * w2.y + h4.z * w2.z + h4.w * w2.w;
          }
          __syncthreads();
        }
      }
      int k = bid * 4 + kl;
      if (k < cHG) {
        int v = subtasks[m * cS + s];
        const float* git = gitab + (size_t)v * cG3;
        float rg = 1.f / (1.f + expf(-(git[k] + accr + b_hh[k])));
        float zg = 1.f / (1.f + expf(-(git[cHG + k] + accz + b_hh[cHG + k])));
        float ng = tanhf(git[2 * cHG + k] + rg * (accn + b_hh[2 * cHG + k]));
        float hp = (s > 0) ? X[((size_t)(m * cS + s - 1)) * cHG + k] : 0.f;
        X[((size_t)(m * cS + s)) * cHG + k] = (1.f - zg) * ng + zg * hp;
      }
    }
    gbar(cnt, gen);
  }

  // ---------------- phase 2: p_init, norms, ps0/r0 ----------------
  if (bid < cN) {
    int n = bid;
    if (tid == 0) sh.tl.anynz = 0;
    __syncthreads();
    int nz = (hxs[n * cOW + tid] != 0.f) ? 1 : 0;
    if (tid + 256 < cOW) nz |= (hxs[n * cOW + tid + 256] != 0.f) ? 1 : 0;
    if (nz) sh.tl.anynz = 1;
    __syncthreads();
    bool newep = (sh.tl.anynz == 0);
    if (tid < cS) {
      const float* xr = X + ((size_t)(n * cS + tid)) * cHG;
      float p0 = xr[1];
      p[n * cS + tid] = newep ? p0 : hxs[n * cOW + 1 + cAN + 1 + cH + tid];
      float sp = 0.f, sm = 0.f;
      for (int h = 0; h < cH; ++h) {
        float vp = xr[2 + 2 * cH + h]; sp += vp * vp;
        float vm = xr[2 + cH + h];     sm += vm * vm;
      }
      nMp[n * cS + tid] = sqrtf(sp);
      nMm[n * cS + tid] = sqrtf(sm);
    }
    __syncthreads();
    ps_r_compute(n, p, X, psb, r, sh.tl.pss, sh.tl.red64, sh.tl.mxs);
  }
  gbar(cnt, gen);

  // ---------------- phase 3: T-scan ----------------
  for (int t = 0; t < cT; ++t) {
    // ---- conv0 (factorized): all 256 blocks = (obq 0..3, n 0..63) ----
    {
      int obq = bid >> 6, n = bid & 63;
      sh.c0.rs[tid] = r[n * cH + tid];
      sh.c0.bs[tid]       = base[((size_t)(t * cN + n)) * 512 + tid];
      sh.c0.bs[tid + 256] = base[((size_t)(t * cN + n)) * 512 + tid + 256];
      __syncthreads();
      for (int half = 0; half < 2; ++half) {
        int ob = obq * 2 + half;                    // 0..7 -> 32 o each
        int o_l = tid >> 3, d = tid & 7;
        float acc = 0.f;
        for (int hc = 0; hc < 8; ++hc) {
          #pragma unroll
          for (int q = 0; q < 8; ++q) {
            int idx = q * 256 + tid;
            int row = idx >> 6, c4 = (idx & 63) * 4;
            *(float4*)&sh.c0.wt[row][c4] =
                *(const float4*)(conv0_w + (size_t)(ob * 32 + row) * 2048 + hc * 256 + c4);
          }
          __syncthreads();
          #pragma unroll
          for (int h2 = 0; h2 < 32; ++h2)
            acc += sh.c0.wt[o_l][h2 * 8 + d] * sh.c0.rs[hc * 32 + h2];
          __syncthreads();
        }
        sh.c0.w0s[o_l][d] = acc;
        __syncthreads();
        int o2 = tid & 31, ijg = tid >> 5;
        float bias = conv0_b[ob * 32 + o2];
        #pragma unroll
        for (int q = 0; q < 8; ++q) {
          int ij = ijg * 8 + q;
          float v = bias;
          #pragma unroll
          for (int d2 = 0; d2 < 8; ++d2) v += sh.c0.w0s[o2][d2] * sh.c0.bs[d2 * 64 + ij];
          x1[((size_t)(n * 64 + ij)) * cH + ob * 32 + o2] = fmaxf(v, 0.f);
        }
        __syncthreads();
      }
    }
    gbar(cnt, gen);

    // ---- x2 = relu(x1 @ W1^T + b1), 64x64 tile, mode0 ----
    {
      int nb = bid & 3, mb = bid >> 2;
      int tm = tid & 15, tj = tid >> 4;
      const float* W = convs_w;
      float acc[4][4] = {{0.f}};
      int lrow = tid >> 2, lcol = (tid & 3) * 4;
      for (int kc = 0; kc < cH; kc += 16) {
        float4 av = *(const float4*)(x1 + (size_t)(mb * 64 + lrow) * cH + kc + lcol);
        float4 wv = *(const float4*)(W + (size_t)(nb * 64 + lrow) * cH + kc + lcol);
        sh.ge.As[lcol][lrow] = av.x; sh.ge.As[lcol + 1][lrow] = av.y;
        sh.ge.As[lcol + 2][lrow] = av.z; sh.ge.As[lcol + 3][lrow] = av.w;
        sh.ge.Bs[lcol][lrow] = wv.x; sh.ge.Bs[lcol + 1][lrow] = wv.y;
        sh.ge.Bs[lcol + 2][lrow] = wv.z; sh.ge.Bs[lcol + 3][lrow] = wv.w;
        __syncthreads();
        #pragma unroll
        for (int kk = 0; kk < 16; ++kk) {
          float4 a4 = *(const float4*)&sh.ge.As[kk][tm * 4];
          float4 b4 = *(const float4*)&sh.ge.Bs[kk][tj * 4];
          acc[0][0] += a4.x * b4.x; acc[0][1] += a4.x * b4.y; acc[0][2] += a4.x * b4.z; acc[0][3] += a4.x * b4.w;
          acc[1][0] += a4.y * b4.x; acc[1][1] += a4.y * b4.y; acc[1][2] += a4.y * b4.z; acc[1][3] += a4.y * b4.w;
          acc[2][0] += a4.z * b4.x; acc[2][1] += a4.z * b4.y; acc[2][2] += a4.z * b4.z; acc[2][3] += a4.z * b4.w;
          acc[3][0] += a4.w * b4.x; acc[3][1] += a4.w * b4.y; acc[3][2] += a4.w * b4.z; acc[3][3] += a4.w * b4.w;
        }
        __syncthreads();
      }
      #pragma unroll
      for (int i = 0; i < 4; ++i) {
        int m = mb * 64 + tm * 4 + i;
        float4 o4;
        o4.x = fmaxf(acc[i][0] + convs_b[nb * 64 + tj * 4 + 0], 0.f);
        o4.y = fmaxf(acc[i][1] + convs_b[nb * 64 + tj * 4 + 1], 0.f);
        o4.z = fmaxf(acc[i][2] + convs_b[nb * 64 + tj * 4 + 2], 0.f);
        o4.w = fmaxf(acc[i][3] + convs_b[nb * 64 + tj * 4 + 3], 0.f);
        *(float4*)(x2 + (size_t)m * cH + nb * 64 + tj * 4) = o4;
      }
    }
    gbar(cnt, gen);

    // ---- x3t = relu(x2 @ W2^T + b2), transposed write (lin K-order) ----
    {
      int nb = bid & 3, mb = bid >> 2;
      int tm = tid & 15, tj = tid >> 4;
      const float* W = convs_w + 65536;
      const float* bi = convs_b + 256;
      float acc[4][4] = {{0.f}};
      int lrow = tid >> 2, lcol = (tid & 3) * 4;
      for (int kc = 0; kc < cH; kc += 16) {
        float4 av = *(const float4*)(x2 + (size_t)(mb * 64 + lrow) * cH + kc + lcol);
        float4 wv = *(const float4*)(W + (size_t)(nb * 64 + lrow) * cH + kc + lcol);
        sh.ge.As[lcol][lrow] = av.x; sh.ge.As[lcol + 1][lrow] = av.y;
        sh.ge.As[lcol + 2][lrow] = av.z; sh.ge.As[lcol + 3][lrow] = av.w;
        sh.ge.Bs[lcol][lrow] = wv.x; sh.ge.Bs[lcol + 1][lrow] = wv.y;
        sh.ge.Bs[lcol + 2][lrow] = wv.z; sh.ge.Bs[lcol + 3][lrow] = wv.w;
        __syncthreads();
        #pragma unroll
        for (int kk = 0; kk < 16; ++kk) {
          float4 a4 = *(const float4*)&sh.ge.As[kk][tm * 4];
          float4 b4 = *(const float4*)&sh.ge.Bs[kk][tj * 4];
          acc[0][0] += a4.x * b4.x; acc[0][1] += a4.x * b4.y; acc[0][2] += a4.x * b4.z; acc[0][3] += a4.x * b4.w;
          acc[1][0] += a4.y * b4.x; acc[1][1] += a4.y * b4.y; acc[1][2] += a4.y * b4.z; acc[1][3] += a4.y * b4.w;
          acc[2][0] += a4.z * b4.x; acc[2][1] += a4.z * b4.y; acc[2][2] += a4.z * b4.z; acc[2][3] += a4.z * b4.w;
          acc[3][0] += a4.w * b4.x; acc[3][1] += a4.w * b4.y; acc[3][2] += a4.w * b4.z; acc[3][3] += a4.w * b4.w;
        }
        __syncthreads();
      }
      #pragma unroll
      for (int j = 0; j < 4; ++j) {
        int o = nb * 64 + tj * 4 + j;
        float bv = bi[o];
        float4 o4;
        o4.x = fmaxf(acc[0][j] + bv, 0.f);
        o4.y = fmaxf(acc[1][j] + bv, 0.f);
        o4.z = fmaxf(acc[2][j] + bv, 0.f);
        o4.w = fmaxf(acc[3][j] + bv, 0.f);
        *(float4*)(x3t + (size_t)mb * (64 * cH) + (size_t)o * 64 + tm * 4) = o4;
      }
    }
    gbar(cnt, gen);

    // ---- lin split-K partials: blocks = (nb 0..3, kcb 0..63) ----
    {
      int nb = bid & 3, kcb = bid >> 2;
      int tm = tid & 15, tj = tid >> 4;
      float acc[4][4] = {{0.f}};
      int lrow = tid >> 2, lcol = (tid & 3) * 4;
      for (int kc = 0; kc < 256; kc += 16) {
        float4 av = *(const float4*)(x3t + (size_t)lrow * 16384 + kcb * 256 + kc + lcol);
        float4 wv = *(const float4*)(lin_w + (size_t)(nb * 64 + lrow) * 16384 + kcb * 256 + kc + lcol);
        sh.ge.As[lcol][lrow] = av.x; sh.ge.As[lcol + 1][lrow] = av.y;
        sh.ge.As[lcol + 2][lrow] = av.z; sh.ge.As[lcol + 3][lrow] = av.w;
        sh.ge.Bs[lcol][lrow] = wv.x; sh.ge.Bs[lcol + 1][lrow] = wv.y;
        sh.ge.Bs[lcol + 2][lrow] = wv.z; sh.ge.Bs[lcol + 3][lrow] = wv.w;
        __syncthreads();
        #pragma unroll
        for (int kk = 0; kk < 16; ++kk) {
          float4 a4 = *(const float4*)&sh.ge.As[kk][tm * 4];
          float4 b4 = *(const float4*)&sh.ge.Bs[kk][tj * 4];
          acc[0][0] += a4.x * b4.x; acc[0][1] += a4.x * b4.y; acc[0][2] += a4.x * b4.z; acc[0][3] += a4.x * b4.w;
          acc[1][0] += a4.y * b4.x; acc[1][1] += a4.y * b4.y; acc[1][2] += a4.y * b4.z; acc[1][3] += a4.y * b4.w;
          acc[2][0] += a4.z * b4.x; acc[2][1] += a4.z * b4.y; acc[2][2] += a4.z * b4.z; acc[2][3] += a4.z * b4.w;
          acc[3][0] += a4.w * b4.x; acc[3][1] += a4.w * b4.y; acc[3][2] += a4.w * b4.z; acc[3][3] += a4.w * b4.w;
        }
        __syncthreads();
      }
      #pragma unroll
      for (int i = 0; i < 4; ++i) {
        int n = tm * 4 + i;
        float4 o4 = make_float4(acc[i][0], acc[i][1], acc[i][2], acc[i][3]);
        *(float4*)(part + ((size_t)kcb * cN + n) * cH + nb * 64 + tj * 4) = o4;
      }
    }
    gbar(cnt, gen);

    // ---- tail: blocks 0..63, one per n ----
    if (bid < cN) {
      int n = bid;
      float* orow = out + ((size_t)(t * cN + n)) * cOW;
      float acc = lin_b[tid];
      for (int kc = 0; kc < 64; ++kc) acc += part[((size_t)(kc * cN + n)) * cH + tid];
      float sv = fmaxf(acc, 0.f);
      sh.tl.ss[tid] = sv;
      orow[1 + cAN + 1 + tid] = sv;
      __syncthreads();
      if (tid < cAN) {
        float a = actor_b[tid];
        const float* wr = actor_w + tid * cH;
        for (int h = 0; h < cH; ++h) a += wr[h] * sh.tl.ss[h];
        sh.tl.lg[tid] = a;
      }
      __syncthreads();
      if (tid < cAN) {
        float m = sh.tl.lg[0];
        for (int i = 1; i < cAN; ++i) m = fmaxf(m, sh.tl.lg[i]);
        sh.tl.dpv[tid] = expf(sh.tl.lg[tid] - m);
      }
      __syncthreads();
      if (tid < cAN) {
        float s = 0.f;
        for (int i = 0; i < cAN; ++i) s += sh.tl.dpv[i];
        float dprob = sh.tl.dpv[tid] / s;
        float nv = (tid < 5) ? 1.f : inter[((size_t)(t * cN + n)) * (cAN - 5) + (tid - 5)];
        sh.tl.nz[tid] = nv;
        sh.tl.pr[tid] = dprob * nv;
      }
      __syncthreads();
      if (tid < cAN) {
        float sp = 0.f, sn = 0.f;
        for (int i = 0; i < cAN; ++i) { sp += sh.tl.pr[i]; sn += sh.tl.nz[i]; }
        float deficit = 1.f - sp;
        float v2 = sh.tl.pr[tid] + (sh.tl.nz[tid] / fmaxf(sn, 1e-12f)) * deficit;
        sh.tl.pr[tid] = fminf(fmaxf(v2, 0.f), 1.f);
      }
      __syncthreads();
      if (tid < cAN) {
        float s = 0.f;
        for (int i = 0; i < cAN; ++i) s += sh.tl.pr[i];
        orow[1 + tid] = sh.tl.pr[tid] / fmaxf(s, 1e-12f);
      }
      int at = actions[t * cN + n];
      {
        float a = psi_b[tid];
        for (int h = 0; h < cH; ++h) a += psip[((size_t)(at * cH + h)) * cH + tid] * sh.tl.ss[h];
        sh.tl.es[tid] = a;
        sh.tl.red[tid] = a * a;
      }
      __syncthreads();
      for (int st = 128; st > 0; st >>= 1) {
        if (tid < st) sh.tl.red[tid] += sh.tl.red[tid + st];
        __syncthreads();
      }
      float enorm = sqrtf(sh.tl.red[0]);
      if (tid == 0) {
        float a = critic_b[0];
        for (int h = 0; h < cH; ++h) a += critic_w[h] * sh.tl.ss[h];
        orow[1 + cAN] = a;
        orow[0] = (float)at;
      }
      if (tid < cS) {
        const float* xr = X + ((size_t)(n * cS + tid)) * cHG;
        float dpp = 0.f, dmm = 0.f;
        for (int h = 0; h < cH; ++h) {
          float ev = sh.tl.es[h];
          dpp += ev * xr[2 + 2 * cH + h];
          dmm += ev * xr[2 + cH + h];
        }
        float cP = dpp / fmaxf(enorm * nMp[n * cS + tid], 1e-8f);
        float cM = dmm / fmaxf(enorm * nMm[n * cS + tid], 1e-8f);
        float cc = xr[0];
        float pn = psb[n * cS + tid] + cc * cP - cc * cM;
        p[n * cS + tid] = pn;
        orow[1 + cAN + 1 + cH + tid] = pn;
      }
      if (t == cT - 1) {
        __threadfence_block();
        __syncthreads();
        float* orow2 = out + (size_t)cT * cN * cOW + (size_t)n * cOW;
        orow2[tid] = orow[tid];
        if (tid + 256 < cOW) orow2[tid + 256] = orow[tid + 256];
      } else {
        __syncthreads();
        ps_r_compute(n, p, X, psb, r, sh.tl.pss, sh.tl.red64, sh.tl.mxs);
      }
    }
    gbar(cnt, gen);
  }
}

// ---------------------------------------------------------------------------
extern "C" void kernel_launch(void* const* d_in, const int* in_sizes, int n_in,
                              void* d_out, int out_size, void* d_ws, size_t ws_size,
                              hipStream_t stream) {
  const float* base     = (const float*)d_in[0];
  const float* inter    = (const float*)d_in[1];
  const float* hxs      = (const float*)d_in[2];
  const float* emb      = (const float*)d_in[3];
  const float* w_ih     = (const float*)d_in[4];
  const float* w_hh     = (const float*)d_in[5];
  const float* b_ih     = (const float*)d_in[6];
  const float* b_hh     = (const float*)d_in[7];
  const float* conv0_w  = (const float*)d_in[8];
  const float* conv0_b  = (const float*)d_in[9];
  const float* convs_w  = (const float*)d_in[10];
  const float* convs_b  = (const float*)d_in[11];
  const float* lin_w    = (const float*)d_in[12];
  const float* lin_b    = (const float*)d_in[13];
  const float* psi_w    = (const float*)d_in[14];
  const float* psi_b    = (const float*)d_in[15];
  const float* actor_w  = (const float*)d_in[16];
  const float* actor_b  = (const float*)d_in[17];
  const float* critic_w = (const float*)d_in[18];
  const float* critic_b = (const float*)d_in[19];
  const int*   subtasks = (const int*)d_in[20];
  const int*   actions  = (const int*)d_in[21];
  float* out = (float*)d_out;
  float* ws  = (float*)d_ws;

  int*   bar   = (int*)ws;                 // [0]=cnt, [1]=gen (64 B reserved)
  float* gitab = ws + 16;
  float* X     = ws + 16 + 73920;          // 73936
  float* psip  = ws + 3227856;
  float* p     = ws + 4276432;
  float* psb   = ws + 4280528;
  float* r     = ws + 4284624;
  float* nMp   = ws + 4301008;
  float* nMm   = ws + 4305104;
  float* x1    = ws + 4309200;             // aliased by lin partials
  float* x2    = ws + 5357776;
  float* x3t   = ws + 6406352;

  hipMemsetAsync(bar, 0, 64, stream);
  k_fused<<<GRID, 256, 0, stream>>>(
      base, inter, hxs, emb, w_ih, w_hh, b_ih, b_hh, conv0_w, conv0_b,
      convs_w, convs_b, lin_w, lin_b, psi_w, psi_b, actor_w, actor_b,
      critic_w, critic_b, subtasks, actions, out,
      bar, bar + 1, gitab, X, psip, p, psb, r, nMp, nMm, x1, x2, x3t);
}